// Round 5
// baseline (2319.761 us; speedup 1.0000x reference)
//
#include <hip/hip_runtime.h>

// LSTM: VOCAB=100, INPUT=512, HIDDEN=1024, BATCH=64, SEQ=512
// out = latent[64][512][1024] f32, then h_f[64][1024], c_f[64][1024]
// v5: sentinel-on-data exchange via 4-slot rotating fp16 buffer (MALL-resident),
//     fragment-ordered (conflict-free) LDS, 2 barriers/step, zx prefetch.

typedef _Float16 f16x8 __attribute__((ext_vector_type(8)));
typedef float    f32x4 __attribute__((ext_vector_type(4)));
typedef unsigned int u32x4 __attribute__((ext_vector_type(4)));

#define VOCABN 100
#define SENTW 0xFEFEFEFEu   // fp16 0xFEFE = NaN; |h|<1 can never encode as NaN

// ---------------- K0: zx_table[v][g*1024+n] = emb[v] . Wg[n,0:512] + b_g[n] ----------------
__global__ void k0_zxtable(const float* __restrict__ emb,
                           const float* __restrict__ Wf, const float* __restrict__ bf,
                           const float* __restrict__ Wi, const float* __restrict__ bi,
                           const float* __restrict__ Wo, const float* __restrict__ bo,
                           const float* __restrict__ Wg, const float* __restrict__ bg_,
                           float* __restrict__ zx) {
  const int bid = blockIdx.x;            // 256 blocks: (gate, 16-unit chunk)
  const int g = bid >> 6, chunk = bid & 63;
  const float* W = (g==0)?Wf:(g==1)?Wi:(g==2)?Wo:Wg;
  const float* B = (g==0)?bf:(g==1)?bi:(g==2)?bo:bg_;
  __shared__ float Wl[16][516];
  const int tid = threadIdx.x;
  for (int i = tid; i < 2048; i += 256) {
    int r = i >> 7, c4 = i & 127;
    float4 v = *(const float4*)&W[(size_t)(chunk*16 + r)*1536 + c4*4];
    Wl[r][c4*4+0]=v.x; Wl[r][c4*4+1]=v.y; Wl[r][c4*4+2]=v.z; Wl[r][c4*4+3]=v.w;
  }
  __syncthreads();
  const int u = tid & 15, vi = tid >> 4;
  for (int v0 = 0; v0 < VOCABN; v0 += 16) {
    int v = v0 + vi;
    if (v < VOCABN) {
      const float* er = emb + (size_t)v*512;
      float acc = 0.f;
      #pragma unroll 8
      for (int k = 0; k < 512; k++) acc += er[k]*Wl[u][k];
      zx[(size_t)v*4096 + g*1024 + chunk*16 + u] = acc + B[chunk*16 + u];
    }
  }
}

// ---------------- K1: Whh fp16 conversion + h0 -> hxbuf slot 3 ----------------
__global__ void k1_prep(const float* __restrict__ Wf, const float* __restrict__ Wi,
                        const float* __restrict__ Wo, const float* __restrict__ Wg,
                        const float* __restrict__ h0,
                        _Float16* __restrict__ Whh, _Float16* __restrict__ hxbuf) {
  const int bid = blockIdx.x, tid = threadIdx.x;
  if (bid < 1024) {
    #pragma unroll
    for (int i = 0; i < 4; i++) {
      int F = bid*1024 + i*256 + tid;            // float4 index, 2^20 total
      int g = F >> 18;
      int rem = F & ((1<<18)-1);
      int n = rem >> 8, k4 = rem & 255;
      const float* W = (g==0)?Wf:(g==1)?Wi:(g==2)?Wo:Wg;
      float4 v = *(const float4*)&W[(size_t)n*1536 + 512 + k4*4];
      _Float16 h4[4] = {(_Float16)v.x,(_Float16)v.y,(_Float16)v.z,(_Float16)v.w};
      *(unsigned long long*)&Whh[((size_t)g<<20) + (n<<10) + (k4<<2)] =
          *(unsigned long long*)h4;
    }
  } else {
    int j = bid - 1024;                          // 64 blocks: h0 -> hxbuf[3]
    int base = j*1024 + tid*4;
    float4 v = *(const float4*)&h0[base];
    _Float16 h4[4] = {(_Float16)v.x,(_Float16)v.y,(_Float16)v.z,(_Float16)v.w};
    *(unsigned long long*)&hxbuf[3*65536 + base] = *(unsigned long long*)h4;
  }
}

// ---------------- Main persistent LSTM: 256 blocks = 8 bg x 32 js, 512 thr ----------------
__global__ __launch_bounds__(512, 2) void lstm_main(
    const int* __restrict__ X, const float* __restrict__ c0,
    const float* __restrict__ zx, const _Float16* __restrict__ Whh,
    _Float16* __restrict__ hxbuf, float* out)
{
  const int bid = blockIdx.x;
  const int bg  = bid >> 5;            // batch group: 8 batches
  const int js  = bid & 31;            // unit slice: 32 units (x4 gates = 128 cols)
  const int tid = threadIdx.x;
  const int w   = tid >> 6;            // wave 0..7
  const int l   = tid & 63;
  const int lm = l & 15, lh = l >> 4;

  __shared__ alignas(16) _Float16 hs[16384];      // 32 kk-chunks x 1KB, fragment order
  __shared__ float zsh[8][132];                   // z exchange [batch][4*32 cols]

  // ---- weights: asm loads -> pinned residency (gate=w>>1, half=w&1) ----
  f16x8 bw[32];
  {
    const _Float16* wp = Whh + ((size_t)(w>>1)<<20)
                       + ((size_t)(js*32 + (w&1)*16 + lm)<<10) + (lh<<3);
    #pragma unroll
    for (int kk = 0; kk < 32; kk++) {
      asm volatile("global_load_dwordx4 %0, %1, off"
                   : "=&v"(bw[kk]) : "v"(wp + kk*32));
    }
    asm volatile("s_waitcnt vmcnt(0)");
    __builtin_amdgcn_sched_barrier(0);
  }

  // staging role: wave w covers kk = {w, w+8, w+16, w+24}; lane l -> row l&7 (dup l&15>=8),
  // k-slot (l>>4)*8
  const int srow = bg*8 + (l & 7);
  const int soff = (w << 6) + ((l >> 4) << 4);      // byte offset within 2KB row
  char* lw = (char*)hs + (w << 10) + (l << 4);      // LDS write base (lane-linear)
  const char* hb = (const char*)hs + (l << 4);      // MFMA read base (lane-linear)

  // gate-phase role (tid<256): one (batch b, unit u)
  const int b = (tid >> 5) & 7, u = tid & 31;
  const int brow = bg*8 + b, ucol = js*32 + u;
  float c = 0.f;
  const int* Xr = nullptr;
  if (tid < 256) {
    c = c0[(size_t)brow*1024 + ucol];
    Xr = X + (size_t)brow*512;
  }
  float* latp = out + (size_t)brow*512*1024 + ucol;

  // zx for t=0 (prefetched one step ahead thereafter)
  float zc0=0.f, zc1=0.f, zc2=0.f, zc3=0.f;
  if (tid < 256) {
    int xv = Xr[0];
    const float* p = zx + (size_t)xv*4096 + ucol;
    zc0 = p[0]; zc1 = p[1024]; zc2 = p[2048]; zc3 = p[3072];
  }

  for (int t = 0; t < 512; t++) {
    // ---- prefetch next step's token contribution ----
    float zn0=0.f, zn1=0.f, zn2=0.f, zn3=0.f;
    if (tid < 256 && t < 511) {
      int xv = Xr[t+1];
      const float* p = zx + (size_t)xv*4096 + ucol;
      zn0 = p[0]; zn1 = p[1024]; zn2 = p[2048]; zn3 = p[3072];
    }

    // ---- stage h_{t-1}: sentinel-polled sc1 loads (slot (t-1)&3; t=0 reads h0 in slot 3) ----
    {
      const char* sb = (const char*)hxbuf + (((t-1)&3) << 17) + srow*2048 + soff;
      u32x4 v0, v1, v2, v3;
      for (;;) {
        asm volatile(
          "global_load_dwordx4 %0, %4, off sc1\n\t"
          "global_load_dwordx4 %1, %4, off offset:512 sc1\n\t"
          "global_load_dwordx4 %2, %4, off offset:1024 sc1\n\t"
          "global_load_dwordx4 %3, %4, off offset:1536 sc1\n\t"
          "s_waitcnt vmcnt(0)"
          : "=&v"(v0), "=&v"(v1), "=&v"(v2), "=&v"(v3)
          : "v"(sb));
        bool bad = (v0.x==SENTW)|(v0.y==SENTW)|(v0.z==SENTW)|(v0.w==SENTW)
                 | (v1.x==SENTW)|(v1.y==SENTW)|(v1.z==SENTW)|(v1.w==SENTW)
                 | (v2.x==SENTW)|(v2.y==SENTW)|(v2.z==SENTW)|(v2.w==SENTW)
                 | (v3.x==SENTW)|(v3.y==SENTW)|(v3.z==SENTW)|(v3.w==SENTW);
        if (!bad) break;
      }
      *(u32x4*)(lw)         = v0;     // kk = w
      *(u32x4*)(lw +  8192) = v1;     // kk = w+8
      *(u32x4*)(lw + 16384) = v2;     // kk = w+16
      *(u32x4*)(lw + 24576) = v3;     // kk = w+24
    }
    __syncthreads();   // S1

    // ---- re-sentinel slot (t-2)&3 (js==0 block of each bg; provably quiescent) ----
    if (js == 0 && t >= 1 && t < 509) {
      unsigned* rp = (unsigned*)((char*)hxbuf + (((t-2)&3) << 17) + bg*16384) + tid*8;
      #pragma unroll
      for (int i = 0; i < 8; i++)
        __hip_atomic_store(rp + i, SENTW, __ATOMIC_RELAXED, __HIP_MEMORY_SCOPE_AGENT);
    }

    // ---- MFMA: z[16x16] per wave, K=1024, lane-linear conflict-free reads ----
    f32x4 a0={0,0,0,0}, a1={0,0,0,0}, a2={0,0,0,0}, a3={0,0,0,0};
    #pragma unroll
    for (int kk = 0; kk < 32; kk += 4) {
      f16x8 x0 = *(const f16x8*)(hb + (kk+0)*1024);
      f16x8 x1 = *(const f16x8*)(hb + (kk+1)*1024);
      f16x8 x2 = *(const f16x8*)(hb + (kk+2)*1024);
      f16x8 x3 = *(const f16x8*)(hb + (kk+3)*1024);
      a0 = __builtin_amdgcn_mfma_f32_16x16x32_f16(x0, bw[kk+0], a0, 0, 0, 0);
      a1 = __builtin_amdgcn_mfma_f32_16x16x32_f16(x1, bw[kk+1], a1, 0, 0, 0);
      a2 = __builtin_amdgcn_mfma_f32_16x16x32_f16(x2, bw[kk+2], a2, 0, 0, 0);
      a3 = __builtin_amdgcn_mfma_f32_16x16x32_f16(x3, bw[kk+3], a3, 0, 0, 0);
    }
    f32x4 z4 = (a0 + a1) + (a2 + a3);
    if (lh < 2) {                      // D rows 0..7 (real batches): row=lh*4+r, col=lm
      #pragma unroll
      for (int r4 = 0; r4 < 4; r4++)
        zsh[lh*4 + r4][(w>>1)*32 + (w&1)*16 + lm] = z4[r4];
    }
    __syncthreads();   // S2

    // ---- gates + state update + fire-and-forget publish ----
    if (tid < 256) {
      float zf = zsh[b][u]      + zc0;
      float zi = zsh[b][32+u]   + zc1;
      float zo = zsh[b][64+u]   + zc2;
      float zg = zsh[b][96+u]   + zc3;
      float fg = 1.f/(1.f + __expf(-zf));
      float ig = 1.f/(1.f + __expf(-zi));
      float og = 1.f/(1.f + __expf(-zo));
      float e2g = __expf(2.f*zg);
      float gg = 1.f - 2.f/(e2g + 1.f);
      c = fg*c + ig*gg;
      float e2c = __expf(2.f*c);
      float h = og*(1.f - 2.f/(e2c + 1.f));

      if (t < 511) {
        _Float16 hf = (_Float16)h;
        unsigned short hu = __builtin_bit_cast(unsigned short, hf);
        unsigned pu = (unsigned)__shfl_xor((int)hu, 1);
        if ((u & 1) == 0) {
          unsigned word = (unsigned)hu | (pu << 16);
          __hip_atomic_store(
              (unsigned*)((char*)hxbuf + ((t&3) << 17) + brow*2048 + ucol*2),
              word, __ATOMIC_RELAXED, __HIP_MEMORY_SCOPE_AGENT);
        }
      }
      __builtin_nontemporal_store(h, latp + (size_t)t*1024);
      if (t == 511) {
        out[33554432 + ((size_t)brow<<10) + ucol] = h;   // h_f
        out[33619968 + ((size_t)brow<<10) + ucol] = c;   // c_f
      }
    }
    zc0 = zn0; zc1 = zn1; zc2 = zn2; zc3 = zn3;
    // no end-of-step barrier needed: S1(t+1) orders staging writes vs MFMA reads,
    // S2 ordered zsh; barrier-arrival implies peer phase completion.
  }
}

extern "C" void kernel_launch(void* const* d_in, const int* in_sizes, int n_in,
                              void* d_out, int out_size, void* d_ws, size_t ws_size,
                              hipStream_t stream) {
  const int*   X   = (const int*)  d_in[0];
  const float* h0  = (const float*)d_in[1];
  const float* c0  = (const float*)d_in[2];
  const float* emb = (const float*)d_in[3];
  const float* Wf  = (const float*)d_in[4];  const float* bf = (const float*)d_in[5];
  const float* Wi  = (const float*)d_in[6];  const float* bi = (const float*)d_in[7];
  const float* Wo  = (const float*)d_in[8];  const float* bo = (const float*)d_in[9];
  const float* Wg  = (const float*)d_in[10]; const float* bg = (const float*)d_in[11];
  float* out = (float*)d_out;

  char* ws = (char*)d_ws;
  float*    zx    = (float*)   ws;                          // 1,638,400 B
  _Float16* Whh   = (_Float16*)(ws + 1638400);              // 8,388,608 B
  _Float16* hxbuf = (_Float16*)(ws + 1638400 + 8388608);    // 4 slots * 131,072 B

  hipMemsetAsync(hxbuf, 0xFE, 4*131072, stream);            // NaN-sentinel all slots
  k0_zxtable<<<256, 256, 0, stream>>>(emb, Wf, bf, Wi, bi, Wo, bo, Wg, bg, zx);
  k1_prep<<<1088, 256, 0, stream>>>(Wf, Wi, Wo, Wg, h0, Whh, hxbuf);
  lstm_main<<<256, 512, 0, stream>>>(X, c0, zx, Whh, hxbuf, out);
}

// Round 7
// 1748.623 us; speedup vs baseline: 1.3266x; 1.3266x over previous
//
#include <hip/hip_runtime.h>

// LSTM: VOCAB=100, INPUT=512, HIDDEN=1024, BATCH=64, SEQ=512
// out = latent[64][512][1024] f32, then h_f[64][1024], c_f[64][1024]
// v7: MALL sentinel exchange (r5 protocol) with wide 16B publish (no write
//     amplification), dup-free staging (A rows 8-15 garbage), 8-slot rotation
//     with producer-owned re-sentinel, launch_bounds(512,1) for resident weights.

typedef _Float16 f16x8 __attribute__((ext_vector_type(8)));
typedef float    f32x4 __attribute__((ext_vector_type(4)));
typedef unsigned int u32x4 __attribute__((ext_vector_type(4)));

#define VOCABN 100
#define SENTW 0xFEFEFEFEu   // fp16 0xFEFE = NaN; |h|<1 can never encode as NaN

// ---------------- K0: zx_table[v][g*1024+n] = emb[v] . Wg[n,0:512] + b_g[n] ----------------
__global__ void k0_zxtable(const float* __restrict__ emb,
                           const float* __restrict__ Wf, const float* __restrict__ bf,
                           const float* __restrict__ Wi, const float* __restrict__ bi,
                           const float* __restrict__ Wo, const float* __restrict__ bo,
                           const float* __restrict__ Wg, const float* __restrict__ bg_,
                           float* __restrict__ zx) {
  const int bid = blockIdx.x;            // 256 blocks: (gate, 16-unit chunk)
  const int g = bid >> 6, chunk = bid & 63;
  const float* W = (g==0)?Wf:(g==1)?Wi:(g==2)?Wo:Wg;
  const float* B = (g==0)?bf:(g==1)?bi:(g==2)?bo:bg_;
  __shared__ float Wl[16][516];
  const int tid = threadIdx.x;
  for (int i = tid; i < 2048; i += 256) {
    int r = i >> 7, c4 = i & 127;
    float4 v = *(const float4*)&W[(size_t)(chunk*16 + r)*1536 + c4*4];
    Wl[r][c4*4+0]=v.x; Wl[r][c4*4+1]=v.y; Wl[r][c4*4+2]=v.z; Wl[r][c4*4+3]=v.w;
  }
  __syncthreads();
  const int u = tid & 15, vi = tid >> 4;
  for (int v0 = 0; v0 < VOCABN; v0 += 16) {
    int v = v0 + vi;
    if (v < VOCABN) {
      const float* er = emb + (size_t)v*512;
      float acc = 0.f;
      #pragma unroll 8
      for (int k = 0; k < 512; k++) acc += er[k]*Wl[u][k];
      zx[(size_t)v*4096 + g*1024 + chunk*16 + u] = acc + B[chunk*16 + u];
    }
  }
}

// ---------------- K1: Whh fp16 conversion + h0 -> hstage slot 7 ----------------
__global__ void k1_prep(const float* __restrict__ Wf, const float* __restrict__ Wi,
                        const float* __restrict__ Wo, const float* __restrict__ Wg,
                        const float* __restrict__ h0,
                        _Float16* __restrict__ Whh, _Float16* __restrict__ hstage) {
  const int bid = blockIdx.x, tid = threadIdx.x;
  if (bid < 1024) {
    #pragma unroll
    for (int i = 0; i < 4; i++) {
      int F = bid*1024 + i*256 + tid;            // float4 index, 2^20 total
      int g = F >> 18;
      int rem = F & ((1<<18)-1);
      int n = rem >> 8, k4 = rem & 255;
      const float* W = (g==0)?Wf:(g==1)?Wi:(g==2)?Wo:Wg;
      float4 v = *(const float4*)&W[(size_t)n*1536 + 512 + k4*4];
      _Float16 h4[4] = {(_Float16)v.x,(_Float16)v.y,(_Float16)v.z,(_Float16)v.w};
      *(unsigned long long*)&Whh[((size_t)g<<20) + (n<<10) + (k4<<2)] =
          *(unsigned long long*)h4;
    }
  } else {
    int j = bid - 1024;                          // 64 blocks: h0 -> slot 7 (= (0-1)&7)
    int base = j*1024 + tid*4;
    float4 v = *(const float4*)&h0[base];
    _Float16 h4[4] = {(_Float16)v.x,(_Float16)v.y,(_Float16)v.z,(_Float16)v.w};
    *(unsigned long long*)&hstage[7*65536 + base] = *(unsigned long long*)h4;
  }
}

// ---------------- Main persistent LSTM: 256 blocks = 8 bg x 32 js, 512 thr ----------------
__global__ __launch_bounds__(512, 1) void lstm_main(
    const int* __restrict__ X, const float* __restrict__ c0,
    const float* __restrict__ zx, const _Float16* __restrict__ Whh,
    _Float16* __restrict__ hstage, float* out)
{
  const int bid = blockIdx.x;
  const int bg  = bid >> 5;            // batch group: 8 batches
  const int js  = bid & 31;            // unit slice: 32 units (x4 gates = 128 cols)
  const int tid = threadIdx.x;
  const int w   = tid >> 6;            // wave 0..7
  const int l   = tid & 63;
  const int lm = l & 15, lh = l >> 4;

  __shared__ alignas(16) _Float16 hs[16384];      // 32 kk-chunks x 1KB, fragment order
  __shared__ float zsh[8][132];                   // z exchange [batch][4*32 cols]

  // ---- weights: asm loads -> pinned residency (gate=w>>1, half=w&1) ----
  f16x8 bw[32];
  {
    const _Float16* wp = Whh + ((size_t)(w>>1)<<20)
                       + ((size_t)(js*32 + (w&1)*16 + lm)<<10) + (lh<<3);
    #pragma unroll
    for (int kk = 0; kk < 32; kk++) {
      asm volatile("global_load_dwordx4 %0, %1, off"
                   : "=&v"(bw[kk]) : "v"(wp + kk*32));
    }
    asm volatile("s_waitcnt vmcnt(0)");
    __builtin_amdgcn_sched_barrier(0);
  }

  // staging role: thread covers chunk kk=4w+lh, row l&7, kslot-pair (l>>3)&1 (32B).
  // No dup: LDS rows 8-15 of each chunk stay garbage (D rows 8-15 discarded).
  const int kk  = 4*w + lh;
  const int srw = l & 7;
  const int kp  = (l >> 3) & 1;
  const unsigned sgoff = (unsigned)((bg*8 + srw)*2048 + kk*64 + kp*32);
  char* lw = (char*)hs + kk*1024 + kp*512 + srw*16;   // writes at +0 and +256
  const char* hb = (const char*)hs + (l << 4);        // MFMA read base (lane-linear)

  // gate-phase role (tid<256): one (batch b, unit u)
  const int b = (tid >> 5) & 7, u = tid & 31;
  const int brow = bg*8 + b, ucol = js*32 + u;
  float c = 0.f, hkeep = 0.f;
  const int* Xr = nullptr;
  if (tid < 256) {
    c = c0[(size_t)brow*1024 + ucol];
    Xr = X + (size_t)brow*512;
  }
  float* latp = out + (size_t)brow*512*1024 + ucol;
  const unsigned pboff = (unsigned)(brow*2048 + (js*32 + (u & 24))*2);

  // zx for t=0 (prefetched one step ahead thereafter)
  float zc0=0.f, zc1=0.f, zc2=0.f, zc3=0.f;
  if (tid < 256) {
    int xv = Xr[0];
    const float* p = zx + (size_t)xv*4096 + ucol;
    zc0 = p[0]; zc1 = p[1024]; zc2 = p[2048]; zc3 = p[3072];
  }

  for (int t = 0; t < 512; t++) {
    // ---- prefetch next step's token contribution ----
    float zn0=0.f, zn1=0.f, zn2=0.f, zn3=0.f;
    if (tid < 256 && t < 511) {
      int xv = Xr[t+1];
      const float* p = zx + (size_t)xv*4096 + ucol;
      zn0 = p[0]; zn1 = p[1024]; zn2 = p[2048]; zn3 = p[3072];
    }

    // ---- stage h_{t-1} from slot (t-1)&7: sc1 loads + sentinel poll ----
    u32x4 va, vb;
    {
      const char* sb = (const char*)hstage + ((unsigned)((t+7)&7) << 17) + sgoff;
      int spin = 0;
      for (;;) {
        asm volatile(
          "global_load_dwordx4 %0, %2, off sc1\n\t"
          "global_load_dwordx4 %1, %2, off offset:16 sc1\n\t"
          "s_waitcnt vmcnt(0)"
          : "=&v"(va), "=&v"(vb) : "v"(sb));
        bool bad = (va.x==SENTW)|(va.y==SENTW)|(va.z==SENTW)|(va.w==SENTW)
                 | (vb.x==SENTW)|(vb.y==SENTW)|(vb.z==SENTW)|(vb.w==SENTW);
        if (!bad || ++spin > (1<<18)) break;     // bounded: fail clean, never hang
      }
    }
    // latent store of h_{t-1}: issued here so its HBM ack drains during S1's
    // straggler wait instead of inside the poll's vmcnt(0).
    if (t > 0 && tid < 256)
      __builtin_nontemporal_store(hkeep, latp + (size_t)(t-1)*1024);
    *(u32x4*)(lw)       = va;
    *(u32x4*)(lw + 256) = vb;
    __syncthreads();   // S1 (orders LDS; drains latent store)

    // ---- MFMA: z[16x16] per wave, K=1024, lane-linear conflict-free reads ----
    f32x4 a0={0,0,0,0}, a1={0,0,0,0}, a2={0,0,0,0}, a3={0,0,0,0};
    #pragma unroll
    for (int k2 = 0; k2 < 32; k2 += 4) {
      f16x8 x0 = *(const f16x8*)(hb + (k2+0)*1024);
      f16x8 x1 = *(const f16x8*)(hb + (k2+1)*1024);
      f16x8 x2 = *(const f16x8*)(hb + (k2+2)*1024);
      f16x8 x3 = *(const f16x8*)(hb + (k2+3)*1024);
      a0 = __builtin_amdgcn_mfma_f32_16x16x32_f16(x0, bw[k2+0], a0, 0, 0, 0);
      a1 = __builtin_amdgcn_mfma_f32_16x16x32_f16(x1, bw[k2+1], a1, 0, 0, 0);
      a2 = __builtin_amdgcn_mfma_f32_16x16x32_f16(x2, bw[k2+2], a2, 0, 0, 0);
      a3 = __builtin_amdgcn_mfma_f32_16x16x32_f16(x3, bw[k2+3], a3, 0, 0, 0);
    }
    f32x4 z4 = (a0 + a1) + (a2 + a3);
    if (lh < 2) {                      // D rows 0..7 (real batches): row=lh*4+r, col=lm
      #pragma unroll
      for (int r4 = 0; r4 < 4; r4++)
        zsh[lh*4 + r4][(w>>1)*32 + (w&1)*16 + lm] = z4[r4];
    }
    __syncthreads();   // S2

    // ---- gates + state update + wide publish (pack 8 fp16 -> 16B sc1 store) ----
    if (tid < 256) {
      float zf = zsh[b][u]      + zc0;
      float zi = zsh[b][32+u]   + zc1;
      float zo = zsh[b][64+u]   + zc2;
      float zg = zsh[b][96+u]   + zc3;
      float fg = 1.f/(1.f + __expf(-zf));
      float ig = 1.f/(1.f + __expf(-zi));
      float og = 1.f/(1.f + __expf(-zo));
      float e2g = __expf(2.f*zg);
      float gg = 1.f - 2.f/(e2g + 1.f);
      c = fg*c + ig*gg;
      float e2c = __expf(2.f*c);
      hkeep = og*(1.f - 2.f/(e2c + 1.f));

      if (t < 511) {
        // butterfly-pack 8 consecutive units' fp16 into one 16B chunk
        unsigned hu = (unsigned)__builtin_bit_cast(unsigned short, (_Float16)hkeep);
        unsigned o1 = (unsigned)__shfl_xor((int)hu, 1);
        unsigned d  = (l & 1) ? ((o1 & 0xffffu) | (hu << 16))
                              : ((hu & 0xffffu) | (o1 << 16));
        unsigned o2 = (unsigned)__shfl_xor((int)d, 2);
        unsigned q0 = (l & 2) ? o2 : d;
        unsigned q1 = (l & 2) ? d : o2;
        unsigned o3a = (unsigned)__shfl_xor((int)q0, 4);
        unsigned o3b = (unsigned)__shfl_xor((int)q1, 4);
        u32x4 pk;
        if (l & 4) { pk[0]=o3a; pk[1]=o3b; pk[2]=q0; pk[3]=q1; }
        else       { pk[0]=q0;  pk[1]=q1;  pk[2]=o3a; pk[3]=o3b; }
        if ((l & 7) == 0) {
          // publish h(t) to slot t&7; re-sentinel OWN bytes of slot (t+4)&7.
          // Safety: sentinel is drained at our S1(t+1) (vmcnt0); any consumer
          // reading slot (t+4)&7 expecting h(t+4) got there by staging h(t+4),
          // which our S1(t+1) strictly precedes. Same-thread same-address
          // ordering keeps sentinel < h(t+4) publish.
          char* pb = (char*)hstage + ((unsigned)( t   &7) << 17) + pboff;
          char* rb = (char*)hstage + ((unsigned)((t+4)&7) << 17) + pboff;
          u32x4 sv; sv[0]=SENTW; sv[1]=SENTW; sv[2]=SENTW; sv[3]=SENTW;
          asm volatile(
            "global_store_dwordx4 %0, %1, off sc1\n\t"
            "global_store_dwordx4 %2, %3, off sc1"
            :: "v"(rb), "v"(sv), "v"(pb), "v"(pk) : "memory");
        }
      }
    }
    zc0 = zn0; zc1 = zn1; zc2 = zn2; zc3 = zn3;
    // no trailing barrier: hs reuse guarded by S2(t) and S1(t+1).
  }

  if (tid < 256) {
    __builtin_nontemporal_store(hkeep, latp + (size_t)511*1024);
    out[33554432 + ((size_t)brow<<10) + ucol] = hkeep;   // h_f
    out[33619968 + ((size_t)brow<<10) + ucol] = c;       // c_f
  }
}

extern "C" void kernel_launch(void* const* d_in, const int* in_sizes, int n_in,
                              void* d_out, int out_size, void* d_ws, size_t ws_size,
                              hipStream_t stream) {
  const int*   X   = (const int*)  d_in[0];
  const float* h0  = (const float*)d_in[1];
  const float* c0  = (const float*)d_in[2];
  const float* emb = (const float*)d_in[3];
  const float* Wf  = (const float*)d_in[4];  const float* bf = (const float*)d_in[5];
  const float* Wi  = (const float*)d_in[6];  const float* bi = (const float*)d_in[7];
  const float* Wo  = (const float*)d_in[8];  const float* bo = (const float*)d_in[9];
  const float* Wg  = (const float*)d_in[10]; const float* bg = (const float*)d_in[11];
  float* out = (float*)d_out;

  char* ws = (char*)d_ws;
  float*    zx     = (float*)   ws;                          // 1,638,400 B
  _Float16* Whh    = (_Float16*)(ws + 1638400);              // 8,388,608 B
  _Float16* hstage = (_Float16*)(ws + 1638400 + 8388608);    // 8 slots * 131,072 B

  hipMemsetAsync(hstage, 0xFE, 8*131072, stream);            // NaN-sentinel all slots
  k0_zxtable<<<256, 256, 0, stream>>>(emb, Wf, bf, Wi, bi, Wo, bo, Wg, bg, zx);
  k1_prep<<<1088, 256, 0, stream>>>(Wf, Wi, Wo, Wg, h0, Whh, hstage);
  lstm_main<<<256, 512, 0, stream>>>(X, c0, zx, Whh, hstage, out);
}